// Round 7
// baseline (716.992 us; speedup 1.0000x reference)
//
#include <hip/hip_runtime.h>
#include <stdint.h>

typedef unsigned short ushort_t;
typedef __attribute__((ext_vector_type(8))) short bf16x8;   // 8 bf16 in 4 VGPRs
typedef __attribute__((ext_vector_type(4))) float f32x4;

#define BKT_SHIFT 8
#define BKT_W     256
#define NB_MAX    512
#define KB_ITERS  32
#define KB_CHUNK  (256 * KB_ITERS)   // 8192 edges per block

// ---------------- small helpers ----------------

__global__ void k_zero2(int* __restrict__ bhist, int nb, float* __restrict__ pooled) {
    int i = blockIdx.x * 256 + threadIdx.x;
    if (i < nb) bhist[i] = 0;
    if (i < 128) pooled[i] = 0.f;
}

__device__ __forceinline__ ushort_t f2bf(float f) {
    union { float f; uint32_t u; } a; a.f = f;
    uint32_t u = a.u;
    uint32_t r = (u + 0x7FFFu + ((u >> 16) & 1u)) >> 16;
    return (ushort_t)r;
}
__device__ __forceinline__ float bf_lo(uint32_t p) { return __uint_as_float(p << 16); }
__device__ __forceinline__ float bf_hi(uint32_t p) { return __uint_as_float(p & 0xFFFF0000u); }

// Wt[n][k] = bf16(W[k][n]) for both layer weights
__global__ __launch_bounds__(256) void kW_conv(const float* __restrict__ W1,
                                               const float* __restrict__ W2,
                                               ushort_t* __restrict__ Wt1,
                                               ushort_t* __restrict__ Wt2) {
    int i = blockIdx.x * 256 + threadIdx.x;   // i < 16384
    int k = i >> 7, nn = i & 127;
    Wt1[nn * 128 + k] = f2bf(W1[i]);
    Wt2[nn * 128 + k] = f2bf(W2[i]);
}

// ---------------- CSR build (bucketed) ----------------

__global__ __launch_bounds__(256) void kA_hist(const int* __restrict__ dst, int E, int NB,
                                               int* __restrict__ bhist) {
    __shared__ int lh[NB_MAX];
    int t = threadIdx.x;
    for (int i = t; i < NB; i += 256) lh[i] = 0;
    __syncthreads();
    for (int e = blockIdx.x * 256 + t; e < E; e += gridDim.x * 256)
        atomicAdd(&lh[dst[e] >> BKT_SHIFT], 1);
    __syncthreads();
    for (int i = t; i < NB; i += 256)
        if (lh[i]) atomicAdd(&bhist[i], lh[i]);
}

__global__ __launch_bounds__(512) void kScanB(const int* __restrict__ bhist, int NB, int E,
                                              int* __restrict__ bbase, int* __restrict__ bcur) {
    __shared__ int s[512];
    int t = threadIdx.x;
    int v = (t < NB) ? bhist[t] : 0;
    s[t] = v;
    __syncthreads();
    for (int off = 1; off < 512; off <<= 1) {
        int x = (t >= off) ? s[t - off] : 0;
        __syncthreads();
        s[t] += x;
        __syncthreads();
    }
    if (t < NB) {
        int ex = s[t] - v;
        bbase[t] = ex;
        bcur[t]  = ex;
    }
    if (t == 0) bbase[NB] = E;
}

// scatter edges into bucket-ordered PACKED array: (src<<8) | (dst & 255)
__global__ __launch_bounds__(256) void kB_bucket(const int* __restrict__ src,
                                                 const int* __restrict__ dst, int E, int NB,
                                                 int* __restrict__ bcur,
                                                 uint32_t* __restrict__ bpack) {
    __shared__ int lh[NB_MAX];
    int t = threadIdx.x;
    for (int i = t; i < NB; i += 256) lh[i] = 0;
    __syncthreads();

    int base = blockIdx.x * KB_CHUNK;
    int dreg[KB_ITERS], rank[KB_ITERS];
#pragma unroll
    for (int i = 0; i < KB_ITERS; i++) {
        int e = base + t + i * 256;
        if (e < E) {
            int d = dst[e];
            dreg[i] = d;
            rank[i] = atomicAdd(&lh[d >> BKT_SHIFT], 1);
        } else {
            dreg[i] = -1; rank[i] = 0;
        }
    }
    __syncthreads();
    for (int i = t; i < NB; i += 256) {
        int c = lh[i];
        lh[i] = c ? atomicAdd(&bcur[i], c) : 0;
    }
    __syncthreads();
#pragma unroll
    for (int i = 0; i < KB_ITERS; i++) {
        int e = base + t + i * 256;
        if (dreg[i] >= 0) {
            int d = dreg[i];
            int pos = lh[d >> BKT_SHIFT] + rank[i];
            bpack[pos] = ((uint32_t)src[e] << 8) | (uint32_t)(d & (BKT_W - 1));
        }
    }
}

// per-bucket fused count + scan + dinv + offs + csr fill
__global__ __launch_bounds__(256) void kC_build(const uint32_t* __restrict__ bpack,
                                                const int* __restrict__ bbase, int NB, int n,
                                                float* __restrict__ dinv,
                                                int* __restrict__ offs,
                                                int* __restrict__ csr) {
    __shared__ int cnt[BKT_W];
    __shared__ int s[BKT_W];
    __shared__ int cur[BKT_W];
    int t = threadIdx.x;
    int b = blockIdx.x;
    int nb0 = b << BKT_SHIFT;
    int wlen = min(BKT_W, n - nb0);
    int e0 = bbase[b], e1 = bbase[b + 1];

    cnt[t] = 0;
    __syncthreads();
    for (int e = e0 + t; e < e1; e += 256)
        atomicAdd(&cnt[bpack[e] & (BKT_W - 1)], 1);
    __syncthreads();

    int v = cnt[t];
    s[t] = v;
    __syncthreads();
    for (int off = 1; off < 256; off <<= 1) {
        int x = (t >= off) ? s[t - off] : 0;
        __syncthreads();
        s[t] += x;
        __syncthreads();
    }
    int myoff = e0 + s[t] - v;
    cur[t] = myoff;
    if (t < wlen) {
        offs[nb0 + t] = myoff;
        dinv[nb0 + t] = rsqrtf((float)(v + 1));
    }
    if (b == NB - 1 && t == 0) offs[n] = e1;
    __syncthreads();

    for (int e = e0 + t; e < e1; e += 256) {
        uint32_t p = bpack[e];
        int pos = atomicAdd(&cur[p & (BKT_W - 1)], 1);
        csr[pos] = (int)(p >> 8);
    }
}

// ---------------- MFMA GEMM: C(shard-major bf16, pre-scaled by dinv) ----------------
// C layout: [8 shards][n rows][16 ch]; shard s holds channels s*16..s*16+15.
// nt column-tile == shard index.
template <bool AF32>
__global__ __launch_bounds__(256) void k_gemm_mfma(const void* __restrict__ Av,
                                                   const ushort_t* __restrict__ Wt,
                                                   const float* __restrict__ dinv,
                                                   ushort_t* __restrict__ C, int n) {
    __shared__ ushort_t al[64 * 136];
    __shared__ ushort_t wl[128 * 136];
    const int t = threadIdx.x;
    const int l = t & 63;
    const int wave = t >> 6;
    const int lane15 = l & 15;
    const int quad = l >> 4;
    const int m0 = blockIdx.x * 64;
    const int rows = min(64, n - m0);

#pragma unroll
    for (int i = 0; i < 8; i++) {
        int f = t + 256 * i;
        int r = f >> 4, c = f & 15;
        *(uint4*)(&wl[r * 136 + c * 8]) = ((const uint4*)Wt)[f];
    }
    if (AF32) {
        // A is row-major fp32 [n][128]
        const float4* Ap = (const float4*)((const float*)Av + (size_t)m0 * 128);
        int nf = rows * 32;
#pragma unroll
        for (int i = 0; i < 8; i++) {
            int f = t + 256 * i;
            float4 v = make_float4(0.f, 0.f, 0.f, 0.f);
            if (f < nf) v = Ap[f];
            ushort4 us;
            us.x = f2bf(v.x); us.y = f2bf(v.y); us.z = f2bf(v.z); us.w = f2bf(v.w);
            int r = f >> 5, c = f & 31;
            *(ushort4*)(&al[r * 136 + c * 4]) = us;
        }
    } else {
        // A is shard-major bf16 [8][n][16]
        const uint4* Hp = (const uint4*)Av;   // uint4 = 8 ch; per (shard,row): 2 uint4s
#pragma unroll
        for (int i = 0; i < 4; i++) {
            int f = t + 256 * i;              // f < 1024
            int s = f >> 7, rem = f & 127;
            int r = rem >> 1, half = rem & 1;
            uint4 v = make_uint4(0, 0, 0, 0);
            if (m0 + r < n) v = Hp[(size_t)(s * n + m0 + r) * 2 + half];
            *(uint4*)(&al[r * 136 + s * 16 + half * 8]) = v;
        }
    }
    __syncthreads();

    f32x4 acc[8];
#pragma unroll
    for (int nt = 0; nt < 8; nt++) acc[nt] = (f32x4){0.f, 0.f, 0.f, 0.f};

    const int arow = wave * 16 + lane15;
#pragma unroll
    for (int kt = 0; kt < 4; kt++) {
        bf16x8 af = *(const bf16x8*)(&al[arow * 136 + kt * 32 + quad * 8]);
#pragma unroll
        for (int nt = 0; nt < 8; nt++) {
            bf16x8 bfr = *(const bf16x8*)(&wl[(nt * 16 + lane15) * 136 + kt * 32 + quad * 8]);
            acc[nt] = __builtin_amdgcn_mfma_f32_16x16x32_bf16(af, bfr, acc[nt], 0, 0, 0);
        }
    }

    const int rbase = m0 + wave * 16 + quad * 4;
    float dsc[4];
#pragma unroll
    for (int r = 0; r < 4; r++)
        dsc[r] = (rbase + r < n) ? dinv[rbase + r] : 0.f;
#pragma unroll
    for (int nt = 0; nt < 8; nt++)
#pragma unroll
        for (int r = 0; r < 4; r++) {
            int row = rbase + r;
            if (row < n)
                C[((size_t)nt * n + row) * 16 + lane15] = f2bf(acc[nt][r] * dsc[r]);
        }
}

// ---------------- Aggregation (XCD-sharded channels) ----------------
// Block handles shard s = blockIdx&7 (pins to one XCD via round-robin dispatch).
// Wave per node; 8 lanes per edge (one 32B slice); 8 edges in flight per load.
__global__ __launch_bounds__(256) void k_agg(const ushort_t* __restrict__ xw,
                                             const int* __restrict__ offsets,
                                             const int* __restrict__ csr,
                                             const float* __restrict__ dinv,
                                             const float* __restrict__ bias,
                                             ushort_t* __restrict__ out, int n, int nchunk) {
    const int t = threadIdx.x;
    const int s = blockIdx.x & 7;
    const int chunk = blockIdx.x >> 3;
    const int wv = t >> 6;
    const int l = t & 63;
    const int grp = l >> 3, sub = l & 7;
    const uint32_t* xs = (const uint32_t*)xw + (size_t)s * n * 8;
    uint32_t* os = (uint32_t*)out + (size_t)s * n * 8;
    const float2 bb = ((const float2*)bias)[s * 8 + sub];
    const int wtot = nchunk * 4;

    for (int v = chunk * 4 + wv; v < n; v += wtot) {
        int e0 = __builtin_amdgcn_readfirstlane(offsets[v]);
        int e1 = __builtin_amdgcn_readfirstlane(offsets[v + 1]);
        float ax = 0.f, ay = 0.f;
        if (grp == 0) {
            uint32_t pv = xs[(size_t)v * 8 + sub];   // self loop
            ax = bf_lo(pv); ay = bf_hi(pv);
        }
        for (int e = e0; e < e1; e += 16) {
            int i0 = e + grp, i1 = e + 8 + grp;
            uint32_t p0 = 0, p1 = 0;
            if (i0 < e1) { int u = csr[i0]; p0 = xs[(size_t)u * 8 + sub]; }
            if (i1 < e1) { int u = csr[i1]; p1 = xs[(size_t)u * 8 + sub]; }
            ax += bf_lo(p0) + bf_lo(p1);
            ay += bf_hi(p0) + bf_hi(p1);
        }
        // reduce the 8 edge-groups (lanes stride 8 share a sub-channel)
        ax += __shfl_xor(ax, 8, 64);  ay += __shfl_xor(ay, 8, 64);
        ax += __shfl_xor(ax, 16, 64); ay += __shfl_xor(ay, 16, 64);
        ax += __shfl_xor(ax, 32, 64); ay += __shfl_xor(ay, 32, 64);
        if (grp == 0) {
            float dv = dinv[v];
            float ox = fmaxf(fmaf(ax, dv, bb.x), 0.f);
            float oy = fmaxf(fmaf(ay, dv, bb.y), 0.f);
            os[(size_t)v * 8 + sub] = ((uint32_t)f2bf(oy) << 16) | (uint32_t)f2bf(ox);
        }
    }
}

// ---------------- Mean pool (shard-major bf16 in) ----------------
__global__ __launch_bounds__(256) void k_pool(const ushort_t* __restrict__ h,
                                              float* __restrict__ pooled, int n) {
    __shared__ float red[512];
    const int t = threadIdx.x;
    const int sub = t & 7;
    const int rg = t >> 3;                  // 32 row-groups per block
    const uint32_t* h32 = (const uint32_t*)h;
    for (int s = 0; s < 8; s++) {
        const uint32_t* base = h32 + (size_t)s * n * 8;
        float sx = 0.f, sy = 0.f;
        for (int r = blockIdx.x * 32 + rg; r < n; r += gridDim.x * 32) {
            uint32_t p = base[(size_t)r * 8 + sub];   // contiguous across the block
            sx += bf_lo(p); sy += bf_hi(p);
        }
        red[t] = sx; red[256 + t] = sy;
        __syncthreads();
        for (int off = 128; off >= 8; off >>= 1) {
            if (t < off) { red[t] += red[t + off]; red[256 + t] += red[256 + t + off]; }
            __syncthreads();
        }
        if (t < 8) {
            atomicAdd(&pooled[s * 16 + t * 2],     red[t]);
            atomicAdd(&pooled[s * 16 + t * 2 + 1], red[256 + t]);
        }
        __syncthreads();
    }
}

__global__ __launch_bounds__(128) void k_fc(const float* __restrict__ pooled,
                                            const float* __restrict__ Wfc,
                                            const float* __restrict__ bfc,
                                            float* __restrict__ out, float invN) {
    int j = threadIdx.x;
    float acc = bfc[j];
    for (int k = 0; k < 128; k++)
        acc = fmaf(pooled[k] * invN, Wfc[k * 128 + j], acc);
    out[j] = acc;
}

// ---------------- launcher ----------------
extern "C" void kernel_launch(void* const* d_in, const int* in_sizes, int n_in,
                              void* d_out, int out_size, void* d_ws, size_t ws_size,
                              hipStream_t stream) {
    const float* x    = (const float*)d_in[0];
    const int*   ei   = (const int*)d_in[1];
    const float* W1   = (const float*)d_in[2];
    const float* b1   = (const float*)d_in[3];
    const float* W2   = (const float*)d_in[4];
    const float* b2   = (const float*)d_in[5];
    const float* Wfc  = (const float*)d_in[6];
    const float* bfc  = (const float*)d_in[7];
    float*       out  = (float*)d_out;

    const int n = in_sizes[0] / 128;
    const int E = in_sizes[1] / 2;
    const int* src = ei;
    const int* dst = ei + E;
    const int NB = (n + BKT_W - 1) >> BKT_SHIFT;

    char* w = (char*)d_ws;
    ushort_t* xw = (ushort_t*)w; w += (size_t)n * 128 * sizeof(ushort_t);
    ushort_t* h  = (ushort_t*)w; w += (size_t)n * 128 * sizeof(ushort_t);
    int*      csr   = (int*)w;      w += (size_t)E * sizeof(int);
    uint32_t* bpack = (uint32_t*)w; w += (size_t)E * sizeof(uint32_t);
    float* dinv = (float*)w;  w += (size_t)n * sizeof(float);
    int*   offs = (int*)w;    w += (size_t)(n + 1) * sizeof(int);
    w = (char*)(((uintptr_t)w + 15) & ~(uintptr_t)15);
    int*   bhist = (int*)w;   w += NB_MAX * sizeof(int);
    int*   bbase = (int*)w;   w += (NB_MAX + 1) * sizeof(int);
    int*   bcur  = (int*)w;   w += NB_MAX * sizeof(int);
    w = (char*)(((uintptr_t)w + 15) & ~(uintptr_t)15);
    float* pooled = (float*)w; w += 128 * sizeof(float);
    ushort_t* Wt1 = (ushort_t*)w; w += 16384 * sizeof(ushort_t);
    ushort_t* Wt2 = (ushort_t*)w; w += 16384 * sizeof(ushort_t);

    const int ntiles64 = (n + 63) / 64;
    const int nchunk = 1024;

    k_zero2<<<2, 256, 0, stream>>>(bhist, NB, pooled);
    kW_conv<<<64, 256, 0, stream>>>(W1, W2, Wt1, Wt2);

    kA_hist<<<1024, 256, 0, stream>>>(dst, E, NB, bhist);
    kScanB<<<1, 512, 0, stream>>>(bhist, NB, E, bbase, bcur);
    kB_bucket<<<(E + KB_CHUNK - 1) / KB_CHUNK, 256, 0, stream>>>(src, dst, E, NB, bcur, bpack);
    kC_build<<<NB, 256, 0, stream>>>(bpack, bbase, NB, n, dinv, offs, csr);

    k_gemm_mfma<true><<<ntiles64, 256, 0, stream>>>(x, Wt1, dinv, xw, n);
    k_agg<<<8 * nchunk, 256, 0, stream>>>(xw, offs, csr, dinv, b1, h, n, nchunk);
    k_gemm_mfma<false><<<ntiles64, 256, 0, stream>>>(h, Wt2, dinv, xw, n);
    k_agg<<<8 * nchunk, 256, 0, stream>>>(xw, offs, csr, dinv, b2, h, n, nchunk);

    k_pool<<<512, 256, 0, stream>>>(h, pooled, n);
    k_fc<<<1, 128, 0, stream>>>(pooled, Wfc, bfc, out, 1.0f / (float)n);
}

// Round 8
// 445.858 us; speedup vs baseline: 1.6081x; 1.6081x over previous
//
#include <hip/hip_runtime.h>
#include <stdint.h>

typedef unsigned short ushort_t;
typedef __attribute__((ext_vector_type(8))) short bf16x8;   // 8 bf16 in 4 VGPRs
typedef __attribute__((ext_vector_type(4))) float f32x4;

#define BKT_SHIFT 8
#define BKT_W     256
#define NB_MAX    512
#define KB_ITERS  32
#define KB_CHUNK  (256 * KB_ITERS)   // 8192 edges per block

// ---------------- helpers ----------------

__device__ __forceinline__ ushort_t f2bf(float f) {
    union { float f; uint32_t u; } a; a.f = f;
    uint32_t u = a.u;
    uint32_t r = (u + 0x7FFFu + ((u >> 16) & 1u)) >> 16;
    return (ushort_t)r;
}
__device__ __forceinline__ float bf_lo(uint32_t p) { return __uint_as_float(p << 16); }
__device__ __forceinline__ float bf_hi(uint32_t p) { return __uint_as_float(p & 0xFFFF0000u); }

// local exclusive scan of bhist[0..NB) into bb[0..512]; call with 256 threads.
// pr[] is 256-int scratch. bb[i] = sum of bhist[0..i); bb covers 512 entries.
__device__ __forceinline__ void local_bucket_scan(const int* __restrict__ bhist, int NB,
                                                  int* pr, int* bb) {
    int t = threadIdx.x;
    int h0 = (2 * t < NB) ? bhist[2 * t] : 0;
    int h1 = (2 * t + 1 < NB) ? bhist[2 * t + 1] : 0;
    pr[t] = h0 + h1;
    __syncthreads();
    for (int off = 1; off < 256; off <<= 1) {
        int x = (t >= off) ? pr[t - off] : 0;
        __syncthreads();
        pr[t] += x;
        __syncthreads();
    }
    int ex = pr[t] - (h0 + h1);          // exclusive over pairs
    bb[2 * t] = ex;
    bb[2 * t + 1] = ex + h0;
    __syncthreads();
}

// ---------------- kW_init: weight convert + zero all small state ----------------
// blocks 0..63: Wt[n][k] = bf16(W[k][n]); block 64: zero bhist/bcnt/pooled/counter.
__global__ __launch_bounds__(256) void kW_init(const float* __restrict__ W1,
                                               const float* __restrict__ W2,
                                               ushort_t* __restrict__ Wt1,
                                               ushort_t* __restrict__ Wt2,
                                               int* __restrict__ bhist,
                                               int* __restrict__ bcnt,
                                               float* __restrict__ pooled,
                                               int* __restrict__ counter) {
    int b = blockIdx.x, t = threadIdx.x;
    if (b < 64) {
        int i = b * 256 + t;              // i < 16384
        int k = i >> 7, nn = i & 127;
        Wt1[nn * 128 + k] = f2bf(W1[i]);
        Wt2[nn * 128 + k] = f2bf(W2[i]);
    } else {
        for (int i = t; i < NB_MAX; i += 256) { bhist[i] = 0; bcnt[i] = 0; }
        if (t < 128) pooled[t] = 0.f;
        if (t == 0) *counter = 0;
    }
}

// ---------------- kA_hist: bucket histogram ----------------
__global__ __launch_bounds__(256) void kA_hist(const int* __restrict__ dst, int E, int NB,
                                               int* __restrict__ bhist) {
    __shared__ int lh[NB_MAX];
    int t = threadIdx.x;
    for (int i = t; i < NB; i += 256) lh[i] = 0;
    __syncthreads();
    for (int e = blockIdx.x * 256 + t; e < E; e += gridDim.x * 256)
        atomicAdd(&lh[dst[e] >> BKT_SHIFT], 1);
    __syncthreads();
    for (int i = t; i < NB; i += 256)
        if (lh[i]) atomicAdd(&bhist[i], lh[i]);
}

// ---------------- kB_bucket: scatter edges into bucket-ordered packed array ----------------
// pack = (src<<8) | (dst & 255). Bucket bases computed by local scan of bhist.
__global__ __launch_bounds__(256) void kB_bucket(const int* __restrict__ src,
                                                 const int* __restrict__ dst, int E, int NB,
                                                 const int* __restrict__ bhist,
                                                 int* __restrict__ bcnt,
                                                 uint32_t* __restrict__ bpack) {
    __shared__ int lh[NB_MAX];
    __shared__ int pr[256];
    __shared__ int bb[NB_MAX];
    int t = threadIdx.x;
    local_bucket_scan(bhist, NB, pr, bb);
    for (int i = t; i < NB; i += 256) lh[i] = 0;
    __syncthreads();

    int base = blockIdx.x * KB_CHUNK;
    int dreg[KB_ITERS], rank[KB_ITERS];
#pragma unroll
    for (int i = 0; i < KB_ITERS; i++) {
        int e = base + t + i * 256;
        if (e < E) {
            int d = dst[e];
            dreg[i] = d;
            rank[i] = atomicAdd(&lh[d >> BKT_SHIFT], 1);
        } else {
            dreg[i] = -1; rank[i] = 0;
        }
    }
    __syncthreads();
    // reserve a contiguous global range per touched bucket
    for (int i = t; i < NB; i += 256) {
        int c = lh[i];
        lh[i] = c ? (bb[i] + atomicAdd(&bcnt[i], c)) : 0;
    }
    __syncthreads();
#pragma unroll
    for (int i = 0; i < KB_ITERS; i++) {
        int e = base + t + i * 256;
        if (dreg[i] >= 0) {
            int d = dreg[i];
            int pos = lh[d >> BKT_SHIFT] + rank[i];
            bpack[pos] = ((uint32_t)src[e] << 8) | (uint32_t)(d & (BKT_W - 1));
        }
    }
}

// ---------------- kC_build: per-bucket count + scan + dinv + offs + csr fill ----------------
__global__ __launch_bounds__(256) void kC_build(const uint32_t* __restrict__ bpack,
                                                const int* __restrict__ bhist, int NB, int n,
                                                float* __restrict__ dinv,
                                                int* __restrict__ offs,
                                                int* __restrict__ csr) {
    __shared__ int pr[256];
    __shared__ int bb[NB_MAX];
    __shared__ int cnt[BKT_W];
    __shared__ int s[BKT_W];
    __shared__ int cur[BKT_W];
    int t = threadIdx.x;
    int b = blockIdx.x;
    local_bucket_scan(bhist, NB, pr, bb);
    int nb0 = b << BKT_SHIFT;
    int wlen = min(BKT_W, n - nb0);
    int e0 = bb[b], e1 = bb[b + 1];

    cnt[t] = 0;
    __syncthreads();
    for (int e = e0 + t; e < e1; e += 256)
        atomicAdd(&cnt[bpack[e] & (BKT_W - 1)], 1);
    __syncthreads();

    int v = cnt[t];
    s[t] = v;
    __syncthreads();
    for (int off = 1; off < 256; off <<= 1) {
        int x = (t >= off) ? s[t - off] : 0;
        __syncthreads();
        s[t] += x;
        __syncthreads();
    }
    int myoff = e0 + s[t] - v;
    cur[t] = myoff;
    if (t < wlen) {
        offs[nb0 + t] = myoff;
        dinv[nb0 + t] = rsqrtf((float)(v + 1));
    }
    if (b == NB - 1 && t == 0) offs[n] = e1;
    __syncthreads();

    for (int e = e0 + t; e < e1; e += 256) {
        uint32_t p = bpack[e];
        int pos = atomicAdd(&cur[p & (BKT_W - 1)], 1);
        csr[pos] = (int)(p >> 8);
    }
}

// ---------------- MFMA GEMM: C[n x 128](bf16 row-major, pre-scaled by dinv) ----------------
template <bool AF32>
__global__ __launch_bounds__(256) void k_gemm_mfma(const void* __restrict__ Av,
                                                   const ushort_t* __restrict__ Wt,
                                                   const float* __restrict__ dinv,
                                                   ushort_t* __restrict__ C, int n) {
    __shared__ ushort_t al[64 * 136];
    __shared__ ushort_t wl[128 * 136];
    const int t = threadIdx.x;
    const int l = t & 63;
    const int wave = t >> 6;
    const int lane15 = l & 15;
    const int quad = l >> 4;
    const int m0 = blockIdx.x * 64;
    const int rows = min(64, n - m0);

#pragma unroll
    for (int i = 0; i < 8; i++) {
        int f = t + 256 * i;
        int r = f >> 4, c = f & 15;
        *(uint4*)(&wl[r * 136 + c * 8]) = ((const uint4*)Wt)[f];
    }
    if (AF32) {
        const float4* Ap = (const float4*)((const float*)Av + (size_t)m0 * 128);
        int nf = rows * 32;
#pragma unroll
        for (int i = 0; i < 8; i++) {
            int f = t + 256 * i;
            float4 v = make_float4(0.f, 0.f, 0.f, 0.f);
            if (f < nf) v = Ap[f];
            ushort4 us;
            us.x = f2bf(v.x); us.y = f2bf(v.y); us.z = f2bf(v.z); us.w = f2bf(v.w);
            int r = f >> 5, c = f & 31;
            *(ushort4*)(&al[r * 136 + c * 4]) = us;
        }
    } else {
        const uint4* Ap = (const uint4*)((const ushort_t*)Av + (size_t)m0 * 128);
        int nf = rows * 16;
#pragma unroll
        for (int i = 0; i < 4; i++) {
            int f = t + 256 * i;
            uint4 v = make_uint4(0, 0, 0, 0);
            if (f < nf) v = Ap[f];
            int r = f >> 4, c = f & 15;
            *(uint4*)(&al[r * 136 + c * 8]) = v;
        }
    }
    __syncthreads();

    f32x4 acc[8];
#pragma unroll
    for (int nt = 0; nt < 8; nt++) acc[nt] = (f32x4){0.f, 0.f, 0.f, 0.f};

    const int arow = wave * 16 + lane15;
#pragma unroll
    for (int kt = 0; kt < 4; kt++) {
        bf16x8 af = *(const bf16x8*)(&al[arow * 136 + kt * 32 + quad * 8]);
#pragma unroll
        for (int nt = 0; nt < 8; nt++) {
            bf16x8 bfr = *(const bf16x8*)(&wl[(nt * 16 + lane15) * 136 + kt * 32 + quad * 8]);
            acc[nt] = __builtin_amdgcn_mfma_f32_16x16x32_bf16(af, bfr, acc[nt], 0, 0, 0);
        }
    }

    const int rbase = m0 + wave * 16 + quad * 4;
    float dsc[4];
#pragma unroll
    for (int r = 0; r < 4; r++)
        dsc[r] = (rbase + r < n) ? dinv[rbase + r] : 0.f;
#pragma unroll
    for (int nt = 0; nt < 8; nt++)
#pragma unroll
        for (int r = 0; r < 4; r++) {
            int row = rbase + r;
            if (row < n) C[(size_t)row * 128 + nt * 16 + lane15] = f2bf(acc[nt][r] * dsc[r]);
        }
}

// ---------------- Aggregation: wave-per-node row-sum, 16-deep gather batches ----------------
__global__ __launch_bounds__(256) void k_agg(const ushort_t* __restrict__ xw,
                                             const int* __restrict__ offsets,
                                             const int* __restrict__ csr,
                                             const float* __restrict__ dinv,
                                             const float* __restrict__ bias,
                                             ushort_t* __restrict__ out, int n) {
    const int l = threadIdx.x & 63;
    const int wave = (blockIdx.x << 2) | (threadIdx.x >> 6);
    const int wstride = gridDim.x << 2;
    const float2 bb = ((const float2*)bias)[l];
    const uint32_t* xw32 = (const uint32_t*)xw;
    uint32_t* out32 = (uint32_t*)out;

    for (int v = wave; v < n; v += wstride) {
        uint32_t pv = xw32[(size_t)v * 64 + l];
        float ax = bf_lo(pv), ay = bf_hi(pv);

        int e  = __builtin_amdgcn_readfirstlane(offsets[v]);
        int e1 = __builtin_amdgcn_readfirstlane(offsets[v + 1]);
        for (; e + 15 < e1; e += 16) {
            int u[16];
#pragma unroll
            for (int i = 0; i < 16; i++) u[i] = __builtin_amdgcn_readfirstlane(csr[e + i]);
            uint32_t p[16];
#pragma unroll
            for (int i = 0; i < 16; i++) p[i] = xw32[(size_t)u[i] * 64 + l];
#pragma unroll
            for (int i = 0; i < 16; i++) { ax += bf_lo(p[i]); ay += bf_hi(p[i]); }
        }
        for (; e + 7 < e1; e += 8) {
            int u[8];
#pragma unroll
            for (int i = 0; i < 8; i++) u[i] = __builtin_amdgcn_readfirstlane(csr[e + i]);
            uint32_t p[8];
#pragma unroll
            for (int i = 0; i < 8; i++) p[i] = xw32[(size_t)u[i] * 64 + l];
#pragma unroll
            for (int i = 0; i < 8; i++) { ax += bf_lo(p[i]); ay += bf_hi(p[i]); }
        }
        for (; e < e1; e++) {
            int u = __builtin_amdgcn_readfirstlane(csr[e]);
            uint32_t p = xw32[(size_t)u * 64 + l];
            ax += bf_lo(p); ay += bf_hi(p);
        }

        float dv = dinv[v];
        float ox = fmaxf(fmaf(ax, dv, bb.x), 0.f);
        float oy = fmaxf(fmaf(ay, dv, bb.y), 0.f);
        out32[(size_t)v * 64 + l] = ((uint32_t)f2bf(oy) << 16) | (uint32_t)f2bf(ox);
    }
}

// ---------------- Fused mean-pool + FC (completion-counter) ----------------
__global__ __launch_bounds__(256) void k_poolfc(const ushort_t* __restrict__ h,
                                                float* __restrict__ pooled, int n,
                                                const float* __restrict__ Wfc,
                                                const float* __restrict__ bfc,
                                                float* __restrict__ out, float invN,
                                                int* __restrict__ counter) {
    __shared__ float red[512];
    __shared__ int lastFlag;
    __shared__ float pl[128];
    const int t = threadIdx.x;
    const int l = t & 63;
    const int wv = (blockIdx.x << 2) | (t >> 6);
    const int ws = gridDim.x << 2;
    const uint32_t* h32 = (const uint32_t*)h;

    const int span = (n + ws - 1) / ws;
    int r0 = wv * span;
    int r1 = min(n, r0 + span);
    float sx = 0.f, sy = 0.f;
    int r = r0;
    for (; r + 3 < r1; r += 4) {
        uint32_t p0 = h32[(size_t)r * 64 + l];
        uint32_t p1 = h32[(size_t)(r + 1) * 64 + l];
        uint32_t p2 = h32[(size_t)(r + 2) * 64 + l];
        uint32_t p3 = h32[(size_t)(r + 3) * 64 + l];
        sx += bf_lo(p0) + bf_lo(p1) + bf_lo(p2) + bf_lo(p3);
        sy += bf_hi(p0) + bf_hi(p1) + bf_hi(p2) + bf_hi(p3);
    }
    for (; r < r1; r++) {
        uint32_t p = h32[(size_t)r * 64 + l];
        sx += bf_lo(p); sy += bf_hi(p);
    }
    red[t] = sx;
    red[256 + t] = sy;
    __syncthreads();
    if (t < 64) {
        sx = red[t] + red[t + 64] + red[t + 128] + red[t + 192];
        sy = red[256 + t] + red[256 + t + 64] + red[256 + t + 128] + red[256 + t + 192];
        atomicAdd(&pooled[2 * l], sx);
        atomicAdd(&pooled[2 * l + 1], sy);
    }
    __threadfence();
    __syncthreads();
    if (t == 0) {
        int old = atomicAdd(counter, 1);
        lastFlag = (old == (int)gridDim.x - 1);
    }
    __syncthreads();
    if (lastFlag) {
        if (t < 128) pl[t] = atomicAdd(&pooled[t], 0.f);   // coherent read across XCDs
        __syncthreads();
        if (t < 128) {
            float acc = bfc[t];
#pragma unroll 8
            for (int k = 0; k < 128; k++)
                acc = fmaf(pl[k] * invN, Wfc[k * 128 + t], acc);
            out[t] = acc;
        }
    }
}

// ---------------- launcher ----------------
extern "C" void kernel_launch(void* const* d_in, const int* in_sizes, int n_in,
                              void* d_out, int out_size, void* d_ws, size_t ws_size,
                              hipStream_t stream) {
    const float* x    = (const float*)d_in[0];
    const int*   ei   = (const int*)d_in[1];
    const float* W1   = (const float*)d_in[2];
    const float* b1   = (const float*)d_in[3];
    const float* W2   = (const float*)d_in[4];
    const float* b2   = (const float*)d_in[5];
    const float* Wfc  = (const float*)d_in[6];
    const float* bfc  = (const float*)d_in[7];
    float*       out  = (float*)d_out;

    const int n = in_sizes[0] / 128;
    const int E = in_sizes[1] / 2;
    const int* src = ei;
    const int* dst = ei + E;
    const int NB = (n + BKT_W - 1) >> BKT_SHIFT;   // 391

    char* w = (char*)d_ws;
    ushort_t* xw = (ushort_t*)w; w += (size_t)n * 128 * sizeof(ushort_t);
    ushort_t* h  = (ushort_t*)w; w += (size_t)n * 128 * sizeof(ushort_t);
    int*      csr   = (int*)w;      w += (size_t)E * sizeof(int);
    uint32_t* bpack = (uint32_t*)w; w += (size_t)E * sizeof(uint32_t);
    float* dinv = (float*)w;  w += (size_t)n * sizeof(float);
    int*   offs = (int*)w;    w += (size_t)(n + 1) * sizeof(int);
    w = (char*)(((uintptr_t)w + 15) & ~(uintptr_t)15);
    int*   bhist = (int*)w;   w += NB_MAX * sizeof(int);
    int*   bcnt  = (int*)w;   w += NB_MAX * sizeof(int);
    int*   counter = (int*)w; w += 4 * sizeof(int);
    float* pooled = (float*)w; w += 128 * sizeof(float);
    ushort_t* Wt1 = (ushort_t*)w; w += 16384 * sizeof(ushort_t);
    ushort_t* Wt2 = (ushort_t*)w; w += 16384 * sizeof(ushort_t);

    const int ntiles64 = (n + 63) / 64;

    kW_init<<<65, 256, 0, stream>>>(W1, W2, Wt1, Wt2, bhist, bcnt, pooled, counter);
    kA_hist<<<1024, 256, 0, stream>>>(dst, E, NB, bhist);
    kB_bucket<<<(E + KB_CHUNK - 1) / KB_CHUNK, 256, 0, stream>>>(src, dst, E, NB, bhist, bcnt, bpack);
    kC_build<<<NB, 256, 0, stream>>>(bpack, bhist, NB, n, dinv, offs, csr);

    k_gemm_mfma<true><<<ntiles64, 256, 0, stream>>>(x, Wt1, dinv, xw, n);
    k_agg<<<8192, 256, 0, stream>>>(xw, offs, csr, dinv, b1, h, n);
    k_gemm_mfma<false><<<ntiles64, 256, 0, stream>>>(h, Wt2, dinv, xw, n);
    k_agg<<<8192, 256, 0, stream>>>(xw, offs, csr, dinv, b2, h, n);

    k_poolfc<<<1024, 256, 0, stream>>>(h, pooled, n, Wfc, bfc, out, 1.0f / (float)n, counter);
}

// Round 9
// 371.342 us; speedup vs baseline: 1.9308x; 1.2007x over previous
//
#include <hip/hip_runtime.h>
#include <stdint.h>

typedef unsigned short ushort_t;
typedef __attribute__((ext_vector_type(8))) short bf16x8;   // 8 bf16 in 4 VGPRs
typedef __attribute__((ext_vector_type(4))) float f32x4;

#define BKT_SHIFT 8
#define BKT_W     256
#define NB_MAX    512
#define KB_ITERS  32
#define KB_CHUNK  (256 * KB_ITERS)   // 8192 edges per block

// ---------------- helpers ----------------

__device__ __forceinline__ ushort_t f2bf(float f) {
    union { float f; uint32_t u; } a; a.f = f;
    uint32_t u = a.u;
    uint32_t r = (u + 0x7FFFu + ((u >> 16) & 1u)) >> 16;
    return (ushort_t)r;
}
__device__ __forceinline__ float bf_lo(uint32_t p) { return __uint_as_float(p << 16); }
__device__ __forceinline__ float bf_hi(uint32_t p) { return __uint_as_float(p & 0xFFFF0000u); }

// local exclusive scan of bhist[0..NB) into bb[0..512]; call with 256 threads.
__device__ __forceinline__ void local_bucket_scan(const int* __restrict__ bhist, int NB,
                                                  int* pr, int* bb) {
    int t = threadIdx.x;
    int h0 = (2 * t < NB) ? bhist[2 * t] : 0;
    int h1 = (2 * t + 1 < NB) ? bhist[2 * t + 1] : 0;
    pr[t] = h0 + h1;
    __syncthreads();
    for (int off = 1; off < 256; off <<= 1) {
        int x = (t >= off) ? pr[t - off] : 0;
        __syncthreads();
        pr[t] += x;
        __syncthreads();
    }
    int ex = pr[t] - (h0 + h1);          // exclusive over pairs
    bb[2 * t] = ex;
    bb[2 * t + 1] = ex + h0;
    __syncthreads();
}

// ---------------- kW_init: weight convert + zero all small state ----------------
__global__ __launch_bounds__(256) void kW_init(const float* __restrict__ W1,
                                               const float* __restrict__ W2,
                                               ushort_t* __restrict__ Wt1,
                                               ushort_t* __restrict__ Wt2,
                                               int* __restrict__ bhist,
                                               int* __restrict__ bcnt,
                                               float* __restrict__ pooled,   // 8*128 slices
                                               int* __restrict__ counter) {
    int b = blockIdx.x, t = threadIdx.x;
    if (b < 64) {
        int i = b * 256 + t;              // i < 16384
        int k = i >> 7, nn = i & 127;
        Wt1[nn * 128 + k] = f2bf(W1[i]);
        Wt2[nn * 128 + k] = f2bf(W2[i]);
    } else {
        for (int i = t; i < NB_MAX; i += 256) { bhist[i] = 0; bcnt[i] = 0; }
        for (int i = t; i < 1024; i += 256) pooled[i] = 0.f;
        if (t == 0) *counter = 0;
    }
}

// ---------------- kA_hist: bucket histogram ----------------
__global__ __launch_bounds__(256) void kA_hist(const int* __restrict__ dst, int E, int NB,
                                               int* __restrict__ bhist) {
    __shared__ int lh[NB_MAX];
    int t = threadIdx.x;
    for (int i = t; i < NB; i += 256) lh[i] = 0;
    __syncthreads();
    for (int e = blockIdx.x * 256 + t; e < E; e += gridDim.x * 256)
        atomicAdd(&lh[dst[e] >> BKT_SHIFT], 1);
    __syncthreads();
    for (int i = t; i < NB; i += 256)
        if (lh[i]) atomicAdd(&bhist[i], lh[i]);
}

// ---------------- kB_bucket: scatter edges into bucket-ordered packed array ----------------
__global__ __launch_bounds__(256) void kB_bucket(const int* __restrict__ src,
                                                 const int* __restrict__ dst, int E, int NB,
                                                 const int* __restrict__ bhist,
                                                 int* __restrict__ bcnt,
                                                 uint32_t* __restrict__ bpack) {
    __shared__ int lh[NB_MAX];
    __shared__ int pr[256];
    __shared__ int bb[NB_MAX];
    int t = threadIdx.x;
    local_bucket_scan(bhist, NB, pr, bb);
    for (int i = t; i < NB; i += 256) lh[i] = 0;
    __syncthreads();

    int base = blockIdx.x * KB_CHUNK;
    int dreg[KB_ITERS], rank[KB_ITERS];
#pragma unroll
    for (int i = 0; i < KB_ITERS; i++) {
        int e = base + t + i * 256;
        if (e < E) {
            int d = dst[e];
            dreg[i] = d;
            rank[i] = atomicAdd(&lh[d >> BKT_SHIFT], 1);
        } else {
            dreg[i] = -1; rank[i] = 0;
        }
    }
    __syncthreads();
    for (int i = t; i < NB; i += 256) {
        int c = lh[i];
        lh[i] = c ? (bb[i] + atomicAdd(&bcnt[i], c)) : 0;
    }
    __syncthreads();
#pragma unroll
    for (int i = 0; i < KB_ITERS; i++) {
        int e = base + t + i * 256;
        if (dreg[i] >= 0) {
            int d = dreg[i];
            int pos = lh[d >> BKT_SHIFT] + rank[i];
            bpack[pos] = ((uint32_t)src[e] << 8) | (uint32_t)(d & (BKT_W - 1));
        }
    }
}

// ---------------- kC_build: per-bucket count + scan + dinv + offs + csr fill ----------------
__global__ __launch_bounds__(256) void kC_build(const uint32_t* __restrict__ bpack,
                                                const int* __restrict__ bhist, int NB, int n,
                                                float* __restrict__ dinv,
                                                int* __restrict__ offs,
                                                int* __restrict__ csr) {
    __shared__ int pr[256];
    __shared__ int bb[NB_MAX];
    __shared__ int cnt[BKT_W];
    __shared__ int s[BKT_W];
    __shared__ int cur[BKT_W];
    int t = threadIdx.x;
    int b = blockIdx.x;
    local_bucket_scan(bhist, NB, pr, bb);
    int nb0 = b << BKT_SHIFT;
    int wlen = min(BKT_W, n - nb0);
    int e0 = bb[b], e1 = bb[b + 1];

    cnt[t] = 0;
    __syncthreads();
    for (int e = e0 + t; e < e1; e += 256)
        atomicAdd(&cnt[bpack[e] & (BKT_W - 1)], 1);
    __syncthreads();

    int v = cnt[t];
    s[t] = v;
    __syncthreads();
    for (int off = 1; off < 256; off <<= 1) {
        int x = (t >= off) ? s[t - off] : 0;
        __syncthreads();
        s[t] += x;
        __syncthreads();
    }
    int myoff = e0 + s[t] - v;
    cur[t] = myoff;
    if (t < wlen) {
        offs[nb0 + t] = myoff;
        dinv[nb0 + t] = rsqrtf((float)(v + 1));
    }
    if (b == NB - 1 && t == 0) offs[n] = e1;
    __syncthreads();

    for (int e = e0 + t; e < e1; e += 256) {
        uint32_t p = bpack[e];
        int pos = atomicAdd(&cur[p & (BKT_W - 1)], 1);
        csr[pos] = (int)(p >> 8);
    }
}

// ---------------- MFMA GEMM: C[n x 128](bf16 row-major, pre-scaled by dinv) ----------------
template <bool AF32>
__global__ __launch_bounds__(256) void k_gemm_mfma(const void* __restrict__ Av,
                                                   const ushort_t* __restrict__ Wt,
                                                   const float* __restrict__ dinv,
                                                   ushort_t* __restrict__ C, int n) {
    __shared__ ushort_t al[64 * 136];
    __shared__ ushort_t wl[128 * 136];
    const int t = threadIdx.x;
    const int l = t & 63;
    const int wave = t >> 6;
    const int lane15 = l & 15;
    const int quad = l >> 4;
    const int m0 = blockIdx.x * 64;
    const int rows = min(64, n - m0);

#pragma unroll
    for (int i = 0; i < 8; i++) {
        int f = t + 256 * i;
        int r = f >> 4, c = f & 15;
        *(uint4*)(&wl[r * 136 + c * 8]) = ((const uint4*)Wt)[f];
    }
    if (AF32) {
        const float4* Ap = (const float4*)((const float*)Av + (size_t)m0 * 128);
        int nf = rows * 32;
#pragma unroll
        for (int i = 0; i < 8; i++) {
            int f = t + 256 * i;
            float4 v = make_float4(0.f, 0.f, 0.f, 0.f);
            if (f < nf) v = Ap[f];
            ushort4 us;
            us.x = f2bf(v.x); us.y = f2bf(v.y); us.z = f2bf(v.z); us.w = f2bf(v.w);
            int r = f >> 5, c = f & 31;
            *(ushort4*)(&al[r * 136 + c * 4]) = us;
        }
    } else {
        const uint4* Ap = (const uint4*)((const ushort_t*)Av + (size_t)m0 * 128);
        int nf = rows * 16;
#pragma unroll
        for (int i = 0; i < 4; i++) {
            int f = t + 256 * i;
            uint4 v = make_uint4(0, 0, 0, 0);
            if (f < nf) v = Ap[f];
            int r = f >> 4, c = f & 15;
            *(uint4*)(&al[r * 136 + c * 8]) = v;
        }
    }
    __syncthreads();

    f32x4 acc[8];
#pragma unroll
    for (int nt = 0; nt < 8; nt++) acc[nt] = (f32x4){0.f, 0.f, 0.f, 0.f};

    const int arow = wave * 16 + lane15;
#pragma unroll
    for (int kt = 0; kt < 4; kt++) {
        bf16x8 af = *(const bf16x8*)(&al[arow * 136 + kt * 32 + quad * 8]);
#pragma unroll
        for (int nt = 0; nt < 8; nt++) {
            bf16x8 bfr = *(const bf16x8*)(&wl[(nt * 16 + lane15) * 136 + kt * 32 + quad * 8]);
            acc[nt] = __builtin_amdgcn_mfma_f32_16x16x32_bf16(af, bfr, acc[nt], 0, 0, 0);
        }
    }

    const int rbase = m0 + wave * 16 + quad * 4;
    float dsc[4];
#pragma unroll
    for (int r = 0; r < 4; r++)
        dsc[r] = (rbase + r < n) ? dinv[rbase + r] : 0.f;
#pragma unroll
    for (int nt = 0; nt < 8; nt++)
#pragma unroll
        for (int r = 0; r < 4; r++) {
            int row = rbase + r;
            if (row < n) C[(size_t)row * 128 + nt * 16 + lane15] = f2bf(acc[nt][r] * dsc[r]);
        }
}

// ---------------- Aggregation: wave-per-node row-sum, 16-deep gather batches ----------------
__global__ __launch_bounds__(256) void k_agg(const ushort_t* __restrict__ xw,
                                             const int* __restrict__ offsets,
                                             const int* __restrict__ csr,
                                             const float* __restrict__ dinv,
                                             const float* __restrict__ bias,
                                             ushort_t* __restrict__ out, int n) {
    const int l = threadIdx.x & 63;
    const int wave = (blockIdx.x << 2) | (threadIdx.x >> 6);
    const int wstride = gridDim.x << 2;
    const float2 bb = ((const float2*)bias)[l];
    const uint32_t* xw32 = (const uint32_t*)xw;
    uint32_t* out32 = (uint32_t*)out;

    for (int v = wave; v < n; v += wstride) {
        uint32_t pv = xw32[(size_t)v * 64 + l];
        float ax = bf_lo(pv), ay = bf_hi(pv);

        int e  = __builtin_amdgcn_readfirstlane(offsets[v]);
        int e1 = __builtin_amdgcn_readfirstlane(offsets[v + 1]);
        for (; e + 15 < e1; e += 16) {
            int u[16];
#pragma unroll
            for (int i = 0; i < 16; i++) u[i] = __builtin_amdgcn_readfirstlane(csr[e + i]);
            uint32_t p[16];
#pragma unroll
            for (int i = 0; i < 16; i++) p[i] = xw32[(size_t)u[i] * 64 + l];
#pragma unroll
            for (int i = 0; i < 16; i++) { ax += bf_lo(p[i]); ay += bf_hi(p[i]); }
        }
        for (; e + 7 < e1; e += 8) {
            int u[8];
#pragma unroll
            for (int i = 0; i < 8; i++) u[i] = __builtin_amdgcn_readfirstlane(csr[e + i]);
            uint32_t p[8];
#pragma unroll
            for (int i = 0; i < 8; i++) p[i] = xw32[(size_t)u[i] * 64 + l];
#pragma unroll
            for (int i = 0; i < 8; i++) { ax += bf_lo(p[i]); ay += bf_hi(p[i]); }
        }
        for (; e < e1; e++) {
            int u = __builtin_amdgcn_readfirstlane(csr[e]);
            uint32_t p = xw32[(size_t)u * 64 + l];
            ax += bf_lo(p); ay += bf_hi(p);
        }

        float dv = dinv[v];
        float ox = fmaxf(fmaf(ax, dv, bb.x), 0.f);
        float oy = fmaxf(fmaf(ay, dv, bb.y), 0.f);
        out32[(size_t)v * 64 + l] = ((uint32_t)f2bf(oy) << 16) | (uint32_t)f2bf(ox);
    }
}

// ---------------- Fused mean-pool + FC (spread-slice atomics + counter) ----------------
// pooled is [8][128]: block b adds into slice b&7 (distinct lines -> low contention).
__global__ __launch_bounds__(256) void k_poolfc(const ushort_t* __restrict__ h,
                                                float* __restrict__ pooled, int n,
                                                const float* __restrict__ Wfc,
                                                const float* __restrict__ bfc,
                                                float* __restrict__ out, float invN,
                                                int* __restrict__ counter) {
    __shared__ float red[512];
    __shared__ int lastFlag;
    __shared__ float pl[128];
    const int t = threadIdx.x;
    const int l = t & 63;
    const int wv = (blockIdx.x << 2) | (t >> 6);
    const int ws = gridDim.x << 2;
    const uint32_t* h32 = (const uint32_t*)h;

    const int span = (n + ws - 1) / ws;
    int r0 = wv * span;
    int r1 = min(n, r0 + span);
    float sx = 0.f, sy = 0.f;
    int r = r0;
    for (; r + 3 < r1; r += 4) {
        uint32_t p0 = h32[(size_t)r * 64 + l];
        uint32_t p1 = h32[(size_t)(r + 1) * 64 + l];
        uint32_t p2 = h32[(size_t)(r + 2) * 64 + l];
        uint32_t p3 = h32[(size_t)(r + 3) * 64 + l];
        sx += bf_lo(p0) + bf_lo(p1) + bf_lo(p2) + bf_lo(p3);
        sy += bf_hi(p0) + bf_hi(p1) + bf_hi(p2) + bf_hi(p3);
    }
    for (; r < r1; r++) {
        uint32_t p = h32[(size_t)r * 64 + l];
        sx += bf_lo(p); sy += bf_hi(p);
    }
    red[t] = sx;
    red[256 + t] = sy;
    __syncthreads();
    float* slice = pooled + (blockIdx.x & 7) * 128;
    if (t < 64) {
        sx = red[t] + red[t + 64] + red[t + 128] + red[t + 192];
        sy = red[256 + t] + red[256 + t + 64] + red[256 + t + 128] + red[256 + t + 192];
        atomicAdd(&slice[2 * l], sx);
        atomicAdd(&slice[2 * l + 1], sy);
    }
    __threadfence();
    __syncthreads();
    if (t == 0) {
        int old = atomicAdd(counter, 1);
        lastFlag = (old == (int)gridDim.x - 1);
    }
    __syncthreads();
    if (lastFlag) {
        if (t < 128) {
            float acc = 0.f;
#pragma unroll
            for (int s = 0; s < 8; s++)
                acc += atomicAdd(&pooled[s * 128 + t], 0.f);   // coherent read
            pl[t] = acc;
        }
        __syncthreads();
        if (t < 128) {
            float acc = bfc[t];
#pragma unroll 8
            for (int k = 0; k < 128; k++)
                acc = fmaf(pl[k] * invN, Wfc[k * 128 + t], acc);
            out[t] = acc;
        }
    }
}

// ---------------- launcher ----------------
extern "C" void kernel_launch(void* const* d_in, const int* in_sizes, int n_in,
                              void* d_out, int out_size, void* d_ws, size_t ws_size,
                              hipStream_t stream) {
    const float* x    = (const float*)d_in[0];
    const int*   ei   = (const int*)d_in[1];
    const float* W1   = (const float*)d_in[2];
    const float* b1   = (const float*)d_in[3];
    const float* W2   = (const float*)d_in[4];
    const float* b2   = (const float*)d_in[5];
    const float* Wfc  = (const float*)d_in[6];
    const float* bfc  = (const float*)d_in[7];
    float*       out  = (float*)d_out;

    const int n = in_sizes[0] / 128;
    const int E = in_sizes[1] / 2;
    const int* src = ei;
    const int* dst = ei + E;
    const int NB = (n + BKT_W - 1) >> BKT_SHIFT;   // 391

    char* w = (char*)d_ws;
    ushort_t* xw = (ushort_t*)w; w += (size_t)n * 128 * sizeof(ushort_t);
    ushort_t* h  = (ushort_t*)w; w += (size_t)n * 128 * sizeof(ushort_t);
    int*      csr   = (int*)w;      w += (size_t)E * sizeof(int);
    uint32_t* bpack = (uint32_t*)w; w += (size_t)E * sizeof(uint32_t);
    float* dinv = (float*)w;  w += (size_t)n * sizeof(float);
    int*   offs = (int*)w;    w += (size_t)(n + 1) * sizeof(int);
    w = (char*)(((uintptr_t)w + 127) & ~(uintptr_t)127);
    int*   bhist = (int*)w;   w += NB_MAX * sizeof(int);
    int*   bcnt  = (int*)w;   w += NB_MAX * sizeof(int);
    int*   counter = (int*)w; w += 32 * sizeof(int);
    float* pooled = (float*)w; w += 8 * 128 * sizeof(float);
    ushort_t* Wt1 = (ushort_t*)w; w += 16384 * sizeof(ushort_t);
    ushort_t* Wt2 = (ushort_t*)w; w += 16384 * sizeof(ushort_t);

    const int ntiles64 = (n + 63) / 64;

    kW_init<<<65, 256, 0, stream>>>(W1, W2, Wt1, Wt2, bhist, bcnt, pooled, counter);
    kA_hist<<<1024, 256, 0, stream>>>(dst, E, NB, bhist);
    kB_bucket<<<(E + KB_CHUNK - 1) / KB_CHUNK, 256, 0, stream>>>(src, dst, E, NB, bhist, bcnt, bpack);
    kC_build<<<NB, 256, 0, stream>>>(bpack, bhist, NB, n, dinv, offs, csr);

    k_gemm_mfma<true><<<ntiles64, 256, 0, stream>>>(x, Wt1, dinv, xw, n);
    k_agg<<<8192, 256, 0, stream>>>(xw, offs, csr, dinv, b1, h, n);
    k_gemm_mfma<false><<<ntiles64, 256, 0, stream>>>(h, Wt2, dinv, xw, n);
    k_agg<<<8192, 256, 0, stream>>>(xw, offs, csr, dinv, b2, h, n);

    k_poolfc<<<256, 256, 0, stream>>>(h, pooled, n, Wfc, bfc, out, 1.0f / (float)n, counter);
}